// Round 3
// baseline (12248.722 us; speedup 1.0000x reference)
//
#include <hip/hip_runtime.h>
#include <hip/hip_bf16.h>
#include <stdint.h>

// ---------------------------------------------------------------------------
// QLSTM: 2-layer LSTM, T=512, B=64, D=512, H=1024, fp32 in/out.
// R3: 128 persistent blocks (64 layer-0 + 64 layer-1), each CU owns the full
// 64-row batch x 16 hidden cols (jt). Weights pinned in VGPRs via asm reg
// barrier (compiler cannot re-materialize). Split per-phase producer/consumer
// counters (64 arrivals each, separate cache lines) replace the 256-way
// central barrier. h rings (depth 8) exchanged via sc0sc1 bypass atomics.
// ---------------------------------------------------------------------------

#define T_STEPS 512
#define HID     1024
#define NBLK    128
#define NTHR    512

typedef __attribute__((ext_vector_type(8)))  short short8;   // 8 bf16
typedef __attribute__((ext_vector_type(16))) float f32x16;   // 32x32 acc

union U16 { unsigned long long u[2]; short8 v; };

// ---- workspace layout (bytes) ----
#define OFF_WIH0 ((size_t)0)          // 4 MB  bf16 [4096][512]
#define OFF_WHH0 ((size_t)4194304)    // 8 MB  bf16 [4096][1024]
#define OFF_WIH1 ((size_t)12582912)   // 8 MB
#define OFF_WHH1 ((size_t)20971520)   // 8 MB
#define OFF_XBF  ((size_t)29360128)   // 33.55 MB bf16 [512][64][512]
#define OFF_H0   ((size_t)62914560)   // ring: 8 x 128 KB  bf16 [64][1024]
#define OFF_H1   ((size_t)(OFF_H0 + 1048576))
#define OFF_CTR  ((size_t)(OFF_H1 + 1048576))   // 513 x 256 B counter lines

// ---------------------------------------------------------------------------
__global__ void cvt_bf16x4(const float4* __restrict__ in,
                           ushort4* __restrict__ out, int n4) {
  int i = blockIdx.x * blockDim.x + threadIdx.x;
  if (i >= n4) return;
  float4 v = in[i];
  __hip_bfloat16 b0 = __float2bfloat16(v.x), b1 = __float2bfloat16(v.y),
                 b2 = __float2bfloat16(v.z), b3 = __float2bfloat16(v.w);
  ushort4 o;
  o.x = *(unsigned short*)&b0; o.y = *(unsigned short*)&b1;
  o.z = *(unsigned short*)&b2; o.w = *(unsigned short*)&b3;
  out[i] = o;
}

__device__ __forceinline__ float sigf(float x) {
  return 1.0f / (1.0f + __expf(-x));
}

__device__ __forceinline__ void spin_ge(const unsigned* a, unsigned t) {
  while (__hip_atomic_load(a, __ATOMIC_RELAXED, __HIP_MEMORY_SCOPE_AGENT) < t)
    __builtin_amdgcn_s_sleep(1);
}

#define ALOAD(p)  __hip_atomic_load((p), __ATOMIC_RELAXED, __HIP_MEMORY_SCOPE_AGENT)

// ---------------------------------------------------------------------------
__launch_bounds__(NTHR, 2)
__global__ void lstm_persist(const __hip_bfloat16* __restrict__ whh0,
                             const __hip_bfloat16* __restrict__ wih0,
                             const __hip_bfloat16* __restrict__ wih1,
                             const __hip_bfloat16* __restrict__ whh1,
                             const __hip_bfloat16* __restrict__ xbf,
                             __hip_bfloat16* h0ring, __hip_bfloat16* h1ring,
                             const float* __restrict__ bih0, const float* __restrict__ bhh0,
                             const float* __restrict__ bih1, const float* __restrict__ bhh1,
                             float* __restrict__ out, unsigned* ctr) {
  __shared__ float dump[8][2][32][32];   // 64 KiB, reused for both mh rounds

  const int tid = threadIdx.x;
  const int w   = tid >> 6;        // wave 0..7
  const int l   = tid & 63;
  const bool L1cu = (blockIdx.x >= 64);
  const int jt = blockIdx.x & 63;  // 16-hidden-col granule; CU owns all 64 rows

  const int n    = l & 31;         // MFMA col (B) / row (A) within tile
  const int ksub = (l >> 5) * 8;
  const bool mm2 = (w >= 4);       // waves 4..7: matmul2 (L0: x@Wih0, L1: h1@Whh1)
  const int wq = w & 3;            // quarter of K within this wave group

  // elementwise identity: (erow, ehc); handles rows erow and erow+32
  const int erow = tid >> 4;           // 0..31
  const int ehc  = tid & 15;           // 0..15
  const int ecol = jt * 16 + ehc;

  float bi, bf_, bg, bo;
  {
    const float* ba = L1cu ? bih1 : bih0;
    const float* bb = L1cu ? bhh1 : bhh0;
    bi  = ba[0 * HID + ecol] + bb[0 * HID + ecol];
    bf_ = ba[1 * HID + ecol] + bb[1 * HID + ecol];
    bg  = ba[2 * HID + ecol] + bb[2 * HID + ecol];
    bo  = ba[3 * HID + ecol] + bb[3 * HID + ecol];
  }
  float cst0 = 0.0f, cst1 = 0.0f;

  // ---- one-time weight preload, then pin in VGPRs ----
  // wave role -> weight matrix and K-range. tile0 = gates{i,f}, tile1 = {g,o}.
  const __hip_bfloat16* Wp = L1cu ? (mm2 ? whh1 : wih1) : (mm2 ? wih0 : whh0);
  const int ldk = (!L1cu && mm2) ? 512 : 1024;
  const int nkc = (!L1cu && mm2) ? 8 : 16;      // kc steps this wave owns
  const int r0 = (n >> 4) * HID + jt * 16 + (n & 15);
  const int r1 = r0 + 2 * HID;

  short8 wA[16], wB[16];
#pragma unroll
  for (int i = 0; i < 16; ++i) {
    int ii = (i < nkc) ? i : (nkc - 1);         // clamp (keeps values defined)
    int k0 = (wq * nkc + ii) * 16 + ksub;
    wA[i] = *(const short8*)(Wp + (size_t)r0 * ldk + k0);
    wB[i] = *(const short8*)(Wp + (size_t)r1 * ldk + k0);
  }
#pragma unroll
  for (int i = 0; i < 16; ++i) {
    asm volatile("" : "+v"(wA[i]));
    asm volatile("" : "+v"(wB[i]));
  }

  const int pbeg = L1cu ? 1 : 0;
  const int pend = L1cu ? T_STEPS : (T_STEPS - 1);

  for (int p = pbeg; p <= pend; ++p) {
    // ---- dependency polls (wave-uniform; all lanes spin on same line) ----
    if (L1cu) {
      spin_ge(ctr + (size_t)(p - 1) * 64, 64u);               // h0[p-1] ready
      if (p >= 2) spin_ge(ctr + (size_t)(p - 1) * 64 + 32, 64u); // h1[p-2] ready
    } else {
      if (p >= 1) spin_ge(ctr + (size_t)(p - 1) * 64, 64u);   // h0[p-1] ready
      if (p >= 8) spin_ge(ctr + (size_t)(p - 7) * 64 + 32, 64u); // ring reuse safe
    }

    f32x16 a00, a01, a10, a11;
#pragma unroll
    for (int r = 0; r < 16; ++r) { a00[r] = 0.f; a01[r] = 0.f; a10[r] = 0.f; a11[r] = 0.f; }

    if (!L1cu && mm2) {
      // ---- x_p @ Wih0^T (K=512 quarter), plain cached loads ----
      const __hip_bfloat16* xb = xbf + (size_t)p * 64 * 512;
#pragma unroll
      for (int i = 0; i < 8; ++i) {
        int k0 = (wq * 8 + i) * 16 + ksub;
        short8 x0 = *(const short8*)(xb + (size_t)n * 512 + k0);
        short8 x1 = *(const short8*)(xb + (size_t)(n + 32) * 512 + k0);
        a00 = __builtin_amdgcn_mfma_f32_32x32x16_bf16(x0, wA[i], a00, 0, 0, 0);
        a01 = __builtin_amdgcn_mfma_f32_32x32x16_bf16(x0, wB[i], a01, 0, 0, 0);
        a10 = __builtin_amdgcn_mfma_f32_32x32x16_bf16(x1, wA[i], a10, 0, 0, 0);
        a11 = __builtin_amdgcn_mfma_f32_32x32x16_bf16(x1, wB[i], a11, 0, 0, 0);
      }
    } else {
      // ---- h @ W^T (K=1024 quarter), sc0sc1 bypass loads ----
      const __hip_bfloat16* hs = (!mm2)
          ? (h0ring + (size_t)((p - 1) & 7) * 65536)    // h0[p-1]
          : (h1ring + (size_t)((p - 2) & 7) * 65536);   // h1[p-2] (L1 only)
#pragma unroll
      for (int i = 0; i < 16; ++i) {
        int k0 = (wq * 16 + i) * 16 + ksub;
        const unsigned long long* q0 = (const unsigned long long*)(hs + (size_t)n * 1024 + k0);
        const unsigned long long* q1 = (const unsigned long long*)(hs + (size_t)(n + 32) * 1024 + k0);
        U16 a0v, a1v;
        a0v.u[0] = ALOAD(q0); a0v.u[1] = ALOAD(q0 + 1);
        a1v.u[0] = ALOAD(q1); a1v.u[1] = ALOAD(q1 + 1);
        a00 = __builtin_amdgcn_mfma_f32_32x32x16_bf16(a0v.v, wA[i], a00, 0, 0, 0);
        a01 = __builtin_amdgcn_mfma_f32_32x32x16_bf16(a0v.v, wB[i], a01, 0, 0, 0);
        a10 = __builtin_amdgcn_mfma_f32_32x32x16_bf16(a1v.v, wA[i], a10, 0, 0, 0);
        a11 = __builtin_amdgcn_mfma_f32_32x32x16_bf16(a1v.v, wB[i], a11, 0, 0, 0);
      }
    }

    // ---- two reduce rounds (mh=0 rows 0..31, mh=1 rows 32..63) ----
    __hip_bfloat16* hdst = L1cu ? (h1ring + (size_t)((p - 1) & 7) * 65536)
                                : (h0ring + (size_t)(p & 7) * 65536);
    float hout[2], cout_[2];
#pragma unroll
    for (int rd = 0; rd < 2; ++rd) {
      __syncthreads();
#pragma unroll
      for (int r = 0; r < 16; ++r) {
        int row = (r & 3) + 8 * (r >> 2) + 4 * (l >> 5);
        dump[w][0][row][n] = rd ? a10[r] : a00[r];
        dump[w][1][row][n] = rd ? a11[r] : a01[r];
      }
      __syncthreads();

      float gi = bi, gf = bf_, gg = bg, go = bo;
#pragma unroll
      for (int ww = 0; ww < 8; ++ww) {
        gi += dump[ww][0][erow][ehc];
        gf += dump[ww][0][erow][ehc + 16];
        gg += dump[ww][1][erow][ehc];
        go += dump[ww][1][erow][ehc + 16];
      }
      float si = sigf(gi), sf = sigf(gf), so = sigf(go);
      float tg = tanhf(gg);
      float c  = rd ? cst1 : cst0;
      c = sf * c + si * tg;
      if (rd) cst1 = c; else cst0 = c;
      float h = so * tanhf(c);
      hout[rd] = h; cout_[rd] = c;

      // coherent bf16 pair store (lanes ehc even/odd pair via shfl_xor)
      __hip_bfloat16 hbf = __float2bfloat16(h);
      unsigned hb = *(const unsigned short*)&hbf;
      unsigned pr = __shfl_xor(hb, 1);
      if ((ehc & 1) == 0) {
        int em = erow + 32 * rd;
        unsigned pv = hb | (pr << 16);
        __hip_atomic_store((unsigned*)(hdst + (size_t)em * 1024 + ecol), pv,
                           __ATOMIC_RELAXED, __HIP_MEMORY_SCOPE_AGENT);
      }
    }

    // ---- drain h stores, signal arrival ----
    asm volatile("s_waitcnt vmcnt(0)" ::: "memory");
    __syncthreads();
    if (tid == 0) {
      unsigned* arr = L1cu ? (ctr + (size_t)p * 64 + 32) : (ctr + (size_t)p * 64);
      __hip_atomic_fetch_add(arr, 1u, __ATOMIC_RELAXED, __HIP_MEMORY_SCOPE_AGENT);
    }

    // ---- deferred output stores (off the critical path) ----
    if (L1cu) {
#pragma unroll
      for (int rd = 0; rd < 2; ++rd) {
        int em = erow + 32 * rd;
        out[((size_t)(p - 1) * 64 + em) * HID + ecol] = hout[rd];
      }
      if (p == T_STEPS) {
#pragma unroll
        for (int rd = 0; rd < 2; ++rd) {
          int em = erow + 32 * rd;
          out[(size_t)T_STEPS * 64 * HID + 2 * 64 * HID + (size_t)em * HID + ecol] = hout[rd];
          out[(size_t)T_STEPS * 64 * HID + 3 * 64 * HID + (size_t)em * HID + ecol] = cout_[rd];
        }
      }
    } else if (p == T_STEPS - 1) {
#pragma unroll
      for (int rd = 0; rd < 2; ++rd) {
        int em = erow + 32 * rd;
        out[(size_t)T_STEPS * 64 * HID + 0 * 64 * HID + (size_t)em * HID + ecol] = hout[rd];
        out[(size_t)T_STEPS * 64 * HID + 1 * 64 * HID + (size_t)em * HID + ecol] = cout_[rd];
      }
    }
  }
}

// ---------------------------------------------------------------------------
extern "C" void kernel_launch(void* const* d_in, const int* in_sizes, int n_in,
                              void* d_out, int out_size, void* d_ws, size_t ws_size,
                              hipStream_t stream) {
  const float* x     = (const float*)d_in[0];
  const float* Wih0  = (const float*)d_in[1];
  const float* Whh0  = (const float*)d_in[2];
  const float* b_ih0 = (const float*)d_in[3];
  const float* b_hh0 = (const float*)d_in[4];
  const float* Wih1  = (const float*)d_in[5];
  const float* Whh1  = (const float*)d_in[6];
  const float* b_ih1 = (const float*)d_in[7];
  const float* b_hh1 = (const float*)d_in[8];
  float* out = (float*)d_out;

  char* ws = (char*)d_ws;
  __hip_bfloat16* wih0p = (__hip_bfloat16*)(ws + OFF_WIH0);
  __hip_bfloat16* whh0p = (__hip_bfloat16*)(ws + OFF_WHH0);
  __hip_bfloat16* wih1p = (__hip_bfloat16*)(ws + OFF_WIH1);
  __hip_bfloat16* whh1p = (__hip_bfloat16*)(ws + OFF_WHH1);
  __hip_bfloat16* xbfp  = (__hip_bfloat16*)(ws + OFF_XBF);
  __hip_bfloat16* h0p   = (__hip_bfloat16*)(ws + OFF_H0);
  __hip_bfloat16* h1p   = (__hip_bfloat16*)(ws + OFF_H1);
  unsigned* ctr         = (unsigned*)(ws + OFF_CTR);

  // zero h rings + counters (ws re-poisoned each call)
  hipMemsetAsync(ws + OFF_H0, 0, 1048576 * 2 + 262144, stream);

  // fp32 -> bf16 row-major copies
  cvt_bf16x4<<<2048,  256, 0, stream>>>((const float4*)Wih0, (ushort4*)wih0p, 2097152 / 4);
  cvt_bf16x4<<<4096,  256, 0, stream>>>((const float4*)Whh0, (ushort4*)whh0p, 4194304 / 4);
  cvt_bf16x4<<<4096,  256, 0, stream>>>((const float4*)Wih1, (ushort4*)wih1p, 4194304 / 4);
  cvt_bf16x4<<<4096,  256, 0, stream>>>((const float4*)Whh1, (ushort4*)whh1p, 4194304 / 4);
  cvt_bf16x4<<<16384, 256, 0, stream>>>((const float4*)x,    (ushort4*)xbfp, 16777216 / 4);

  void* args[] = { &whh0p, &wih0p, &wih1p, &whh1p, &xbfp, &h0p, &h1p,
                   (void*)&b_ih0, (void*)&b_hh0, (void*)&b_ih1, (void*)&b_hh1,
                   &out, &ctr };
  hipLaunchCooperativeKernel((const void*)lstm_persist, dim3(NBLK), dim3(NTHR),
                             args, 0, stream);
}